// Round 6
// baseline (194.487 us; speedup 1.0000x reference)
//
#include <hip/hip_runtime.h>

#define F 2048
#define BATCH 1024
#define REP_K1 16
#define REP_K2 3

typedef short bf16x8 __attribute__((ext_vector_type(8)));
typedef float f32x4 __attribute__((ext_vector_type(4)));
typedef unsigned short u16x4 __attribute__((ext_vector_type(4)));

// round-to-nearest-even f32 -> bf16 (bit trick, finite values only)
__device__ __forceinline__ unsigned short f2bf(float f) {
  unsigned u = __builtin_bit_cast(unsigned, f);
  unsigned r = (u + 0x7fffu + ((u >> 16) & 1u)) >> 16;
  return (unsigned short)r;
}

__device__ __forceinline__ void gload_lds16(const void* g, void* l) {
  __builtin_amdgcn_global_load_lds(
      (const __attribute__((address_space(1))) unsigned int*)g,
      (__attribute__((address_space(3))) unsigned int*)l,
      16, 0, 0);
}

// ---------------------------------------------------------------------------
// K1: fused prep+convert.  DIAGNOSTIC: body repeated REP_K1 times (idempotent)
// so the kernel exceeds the 44us harness fills and appears in rocprof top-5.
// Per-rep cost = row dur / REP_K1.
// blocks [0,1024): convert inputs f32 -> bf16, 2048 elems/block.
// blocks [1024,1536): prep, one wave per weight row (4 rows/block):
//   w = exp(weight) in diag 32-block, weight below, 0 above
//   w_n = exp(dw)*w/||w|| bf16, zero-padded out to 128-col multiple (BK=128)
//   exp_blocks[r,p] = exp(dw + weight[r,d0+p] - 0.5*log(wsn))
// ---------------------------------------------------------------------------
__global__ __launch_bounds__(256) void prep_convert_kernel(
    const float* __restrict__ inputs, unsigned short* __restrict__ a_bf,
    const float* __restrict__ weight, const float* __restrict__ dw,
    unsigned short* __restrict__ w_n, float* __restrict__ exp_blocks)
{
  for (int rep = 0; rep < REP_K1; ++rep) {
    int bid = blockIdx.x;
    if (bid < 1024) {
      int idx = bid * 2048 + threadIdx.x * 8;
      float4 v0 = *(const float4*)(inputs + idx);
      float4 v1 = *(const float4*)(inputs + idx + 4);
      union { unsigned short s[8]; bf16x8 v; } o;
      o.s[0] = f2bf(v0.x); o.s[1] = f2bf(v0.y); o.s[2] = f2bf(v0.z); o.s[3] = f2bf(v0.w);
      o.s[4] = f2bf(v1.x); o.s[5] = f2bf(v1.y); o.s[6] = f2bf(v1.z); o.s[7] = f2bf(v1.w);
      *(bf16x8*)(a_bf + idx) = o.v;
    } else {
      int rb = bid - 1024;
      int lane = threadIdx.x & 63;
      int r = rb * 4 + (threadIdx.x >> 6);
      int i = r >> 5;
      int lim = (i + 1) * 32;             // valid-data end (mult of 32)
      int wlim = (r & ~63) + 64;          // gemm-needed end (mult of 64)
      int wzero = (wlim + 127) & ~127;    // zero-pad end for BK=128 staging
      int d0 = i * 32;
      const float* wrow = weight + (size_t)r * F;

      float ss = 0.f;
      for (int j = lane; j < lim / 4; j += 64) {
        float4 v = ((const float4*)wrow)[j];
        if (j * 4 >= d0) {
          v.x = __expf(v.x); v.y = __expf(v.y); v.z = __expf(v.z); v.w = __expf(v.w);
        }
        ss += v.x * v.x + v.y * v.y + v.z * v.z + v.w * v.w;
      }
#pragma unroll
      for (int d = 32; d > 0; d >>= 1) ss += __shfl_xor(ss, d, 64);

      float dwr = dw[r];
      float scale = __expf(dwr) * rsqrtf(ss);
      float halflog = 0.5f * __logf(ss);

      unsigned short* onrow = w_n + (size_t)r * F;
      for (int j = lane; j < wzero / 4; j += 64) {
        u16x4 o = {0, 0, 0, 0};
        if (j * 4 < lim) {
          float4 v = ((const float4*)wrow)[j];
          if (j * 4 >= d0) {
            v.x = __expf(v.x); v.y = __expf(v.y); v.z = __expf(v.z); v.w = __expf(v.w);
          }
          o[0] = f2bf(scale * v.x); o[1] = f2bf(scale * v.y);
          o[2] = f2bf(scale * v.z); o[3] = f2bf(scale * v.w);
        }
        *(u16x4*)(onrow + j * 4) = o;
      }
      if (lane < 32) {
        exp_blocks[(size_t)r * 32 + lane] = __expf(dwr + wrow[d0 + lane] - halflog);
      }
    }
  }
}

// ---------------------------------------------------------------------------
// K2: fused gemm (bf16 MFMA, BK=128) + logdet.
// DIAGNOSTIC: body repeated REP_K2 times (idempotent) for rocprof visibility.
// gemm: out[b,r] = sum_c A[b,c]*W[r,c] + bias[r]   (NT, K-major)
//   64x64 tile, BK=128, 4 waves x (32x32, 2x2 frags of 16x16x32).
//   2-stage pipeline, counted vmcnt(8), raw s_barrier, 16-chunk XOR swizzle.
//   Triangular K: nkt = ceil((tn+1)/2) BK-steps (W zero-padded to 128-mult).
//   tm&8 flip pairs complementary tiles on one CU.
// logdet: block -> i = id&63, 4 batch-groups of 32; eb in LDS (stride 36).
//   ld[b,i,o] = log( sum_p eb[i,o,p] * exp(grad[b,i,p]) )
// ---------------------------------------------------------------------------
__global__ __launch_bounds__(256) void gemm_logdet_kernel(
    const unsigned short* __restrict__ A, const unsigned short* __restrict__ W,
    const float* __restrict__ bias, const float* __restrict__ grad,
    const float* __restrict__ exp_blocks, float* __restrict__ out,
    float* __restrict__ ld)
{
  __shared__ __align__(16) char smem[2 * 32768];  // 64 KiB -> 2 blocks/CU

  int id = blockIdx.x;
  int tm = id >> 5;
  int tn_raw = id & 31;
  int tn = (tm & 8) ? (31 - tn_raw) : tn_raw;
  int m0 = tm * 64, n0 = tn * 64;
  int nkt = (tn + 2) >> 1;             // ceil((tn+1)*64 / 128)

  int tid = threadIdx.x;
  int lane = tid & 63, wid = tid >> 6;
  int wm = wid >> 1, wn = wid & 1;
  int l15 = lane & 15, lg = lane >> 4;
  int srow = lane >> 4;                // staging: 4 rows per instr
  int slot = lane & 15;

  for (int rep = 0; rep < REP_K2; ++rep) {
    __syncthreads();                   // protect smem across reps

    auto stage = [&](int buf, int kt) {
      size_t kb = (size_t)kt * 256;    // byte offset in K (BK=128 bf16)
      char* base = smem + buf * 32768;
#pragma unroll
      for (int e = 0; e < 4; ++e) {
        int s = wid * 4 + e;           // 16 groups of 4 rows
        int row = s * 4 + srow;
        int chunk = slot ^ (row & 7);  // source-side inverse swizzle
        gload_lds16((const char*)A + (size_t)(m0 + row) * 4096 + kb + chunk * 16,
                    base + s * 1024);
        gload_lds16((const char*)W + (size_t)(n0 + row) * 4096 + kb + chunk * 16,
                    base + 16384 + s * 1024);
      }
    };

    f32x4 acc[2][2] = {};

    auto compute = [&](int buf) {
      const char* sA = smem + buf * 32768;
      const char* sB = sA + 16384;
      bf16x8 af[2][4], bfr[2][4];
#pragma unroll
      for (int mi = 0; mi < 2; ++mi) {
        int row = wm * 32 + mi * 16 + l15;
#pragma unroll
        for (int ks = 0; ks < 4; ++ks) {
          int ch = (ks * 4 + lg) ^ (row & 7);
          af[mi][ks] = *(const bf16x8*)(sA + row * 256 + ch * 16);
        }
      }
#pragma unroll
      for (int ni = 0; ni < 2; ++ni) {
        int row = wn * 32 + ni * 16 + l15;
#pragma unroll
        for (int ks = 0; ks < 4; ++ks) {
          int ch = (ks * 4 + lg) ^ (row & 7);
          bfr[ni][ks] = *(const bf16x8*)(sB + row * 256 + ch * 16);
        }
      }
#pragma unroll
      for (int ks = 0; ks < 4; ++ks)
#pragma unroll
        for (int mi = 0; mi < 2; ++mi)
#pragma unroll
          for (int ni = 0; ni < 2; ++ni)
            acc[mi][ni] = __builtin_amdgcn_mfma_f32_16x16x32_bf16(
                af[mi][ks], bfr[ni][ks], acc[mi][ni], 0, 0, 0);
    };

    stage(0, 0);
    for (int kt = 0; kt < nkt; ++kt) {
      if (kt + 1 < nkt) {
        stage((kt + 1) & 1, kt + 1);
        asm volatile("s_waitcnt vmcnt(8)" ::: "memory");   // stage kt landed
      } else {
        asm volatile("s_waitcnt vmcnt(0)" ::: "memory");
      }
      __builtin_amdgcn_s_barrier();
      compute(kt & 1);
      __builtin_amdgcn_s_barrier();    // reads done before buf reuse
    }

    float bv0 = bias[n0 + wn * 32 + l15];
    float bv1 = bias[n0 + wn * 32 + 16 + l15];
#pragma unroll
    for (int mi = 0; mi < 2; ++mi)
#pragma unroll
      for (int ni = 0; ni < 2; ++ni) {
        float bv = ni ? bv1 : bv0;
#pragma unroll
        for (int j = 0; j < 4; ++j) {
          int m = m0 + wm * 32 + mi * 16 + lg * 4 + j;   // C/D: row=(lane>>4)*4+reg
          int n = n0 + wn * 32 + ni * 16 + l15;          //      col=lane&15
          out[(size_t)m * F + n] = acc[mi][ni][j] + bv;
        }
      }

    // ---------------- logdet ----------------
    float* eb = (float*)smem;                  // [32][36] padded
    float* eg = (float*)(smem + 32 * 36 * 4);  // [32][32]
    int li = id & 63;
    int bg0 = (id >> 6) * 4;
    int p = tid & 31, row8 = tid >> 5;

#pragma unroll
    for (int k = 0; k < 4; ++k) {
      int t = tid + k * 256;
      eb[(t >> 5) * 36 + (t & 31)] = exp_blocks[(size_t)li * 1024 + t];
    }

#pragma unroll
    for (int g4 = 0; g4 < 4; ++g4) {
      int b0 = (bg0 + g4) * 32;
      __syncthreads();                 // eb visible / prev-iter eg reads done
#pragma unroll
      for (int k = 0; k < 4; ++k) {
        int bb = b0 + row8 + 8 * k;
        eg[(row8 + 8 * k) * 32 + p] = __expf(grad[((size_t)bb * 64 + li) * 32 + p]);
      }
      __syncthreads();
      float s[4] = {0.f, 0.f, 0.f, 0.f};
#pragma unroll
      for (int q4 = 0; q4 < 8; ++q4) {
        f32x4 e = *(const f32x4*)(eb + p * 36 + q4 * 4);
#pragma unroll
        for (int k = 0; k < 4; ++k) {
          f32x4 g = *(const f32x4*)(eg + (row8 + 8 * k) * 32 + q4 * 4);  // broadcast
          s[k] += e[0] * g[0] + e[1] * g[1] + e[2] * g[2] + e[3] * g[3];
        }
      }
#pragma unroll
      for (int k = 0; k < 4; ++k) {
        int bb = b0 + row8 + 8 * k;
        ld[((size_t)bb * 64 + li) * 32 + p] = __logf(s[k]);
      }
    }
  }
}

// ---------------------------------------------------------------------------
extern "C" void kernel_launch(void* const* d_in, const int* in_sizes, int n_in,
                              void* d_out, int out_size, void* d_ws, size_t ws_size,
                              hipStream_t stream)
{
  const float* inputs = (const float*)d_in[0];
  const float* grad   = (const float*)d_in[1];
  const float* weight = (const float*)d_in[2];
  const float* dw     = (const float*)d_in[3];
  const float* bias   = (const float*)d_in[4];

  float* out = (float*)d_out;                  // 1024*2048
  float* ld  = out + (size_t)BATCH * F;        // 1024*64*32

  unsigned short* w_n  = (unsigned short*)d_ws;              // 8 MiB
  unsigned short* a_bf = w_n + (size_t)F * F;                // 4 MiB
  float* exp_blocks    = (float*)(a_bf + (size_t)BATCH * F); // 256 KiB

  prep_convert_kernel<<<1536, 256, 0, stream>>>(inputs, a_bf, weight, dw, w_n, exp_blocks);
  gemm_logdet_kernel<<<512, 256, 0, stream>>>(a_bf, w_n, bias, grad, exp_blocks, out, ld);
}

// Round 7
// 99.875 us; speedup vs baseline: 1.9473x; 1.9473x over previous
//
#include <hip/hip_runtime.h>

#define F 2048
#define BATCH 1024

typedef short bf16x8 __attribute__((ext_vector_type(8)));
typedef float f32x4 __attribute__((ext_vector_type(4)));
typedef unsigned short u16x4 __attribute__((ext_vector_type(4)));

// round-to-nearest-even f32 -> bf16 (bit trick, finite values only)
__device__ __forceinline__ unsigned short f2bf(float f) {
  unsigned u = __builtin_bit_cast(unsigned, f);
  unsigned r = (u + 0x7fffu + ((u >> 16) & 1u)) >> 16;
  return (unsigned short)r;
}

__device__ __forceinline__ void gload_lds16(const void* g, void* l) {
  __builtin_amdgcn_global_load_lds(
      (const __attribute__((address_space(1))) unsigned int*)g,
      (__attribute__((address_space(3))) unsigned int*)l,
      16, 0, 0);
}

// ---------------------------------------------------------------------------
// K1: fused prep+convert (measured 4.2 us/rep, ~BW-bound; unchanged logic).
// blocks [0,1024): convert inputs f32 -> bf16, 2048 elems/block.
// blocks [1024,1536): prep, one wave per weight row:
//   w = exp(weight) in diag 32-block, weight below, 0 above
//   w_n = exp(dw)*w/||w|| bf16, written for c < (r&~63)+64 (= gemm K-range)
//   exp_blocks[r,p] = exp(dw + weight[r,d0+p] - 0.5*log(wsn))
// ---------------------------------------------------------------------------
__global__ __launch_bounds__(256) void prep_convert_kernel(
    const float* __restrict__ inputs, unsigned short* __restrict__ a_bf,
    const float* __restrict__ weight, const float* __restrict__ dw,
    unsigned short* __restrict__ w_n, float* __restrict__ exp_blocks)
{
  int bid = blockIdx.x;
  if (bid < 1024) {
    int idx = bid * 2048 + threadIdx.x * 8;
    float4 v0 = *(const float4*)(inputs + idx);
    float4 v1 = *(const float4*)(inputs + idx + 4);
    union { unsigned short s[8]; bf16x8 v; } o;
    o.s[0] = f2bf(v0.x); o.s[1] = f2bf(v0.y); o.s[2] = f2bf(v0.z); o.s[3] = f2bf(v0.w);
    o.s[4] = f2bf(v1.x); o.s[5] = f2bf(v1.y); o.s[6] = f2bf(v1.z); o.s[7] = f2bf(v1.w);
    *(bf16x8*)(a_bf + idx) = o.v;
    return;
  }
  int rb = bid - 1024;
  int lane = threadIdx.x & 63;
  int r = rb * 4 + (threadIdx.x >> 6);
  int i = r >> 5;
  int lim = (i + 1) * 32;             // valid-data end (mult of 32)
  int wlim = (r & ~63) + 64;          // gemm K-range end (mult of 64)
  int d0 = i * 32;
  const float* wrow = weight + (size_t)r * F;

  float ss = 0.f;
  for (int j = lane; j < lim / 4; j += 64) {
    float4 v = ((const float4*)wrow)[j];
    if (j * 4 >= d0) {
      v.x = __expf(v.x); v.y = __expf(v.y); v.z = __expf(v.z); v.w = __expf(v.w);
    }
    ss += v.x * v.x + v.y * v.y + v.z * v.z + v.w * v.w;
  }
#pragma unroll
  for (int d = 32; d > 0; d >>= 1) ss += __shfl_xor(ss, d, 64);

  float dwr = dw[r];
  float scale = __expf(dwr) * rsqrtf(ss);
  float halflog = 0.5f * __logf(ss);

  unsigned short* onrow = w_n + (size_t)r * F;
  for (int j = lane; j < wlim / 4; j += 64) {
    u16x4 o = {0, 0, 0, 0};
    if (j * 4 < lim) {
      float4 v = ((const float4*)wrow)[j];
      if (j * 4 >= d0) {
        v.x = __expf(v.x); v.y = __expf(v.y); v.z = __expf(v.z); v.w = __expf(v.w);
      }
      o[0] = f2bf(scale * v.x); o[1] = f2bf(scale * v.y);
      o[2] = f2bf(scale * v.z); o[3] = f2bf(scale * v.w);
    }
    *(u16x4*)(onrow + j * 4) = o;
  }
  if (lane < 32) {
    exp_blocks[(size_t)r * 32 + lane] = __expf(dwr + wrow[d0 + lane] - halflog);
  }
}

// ---------------------------------------------------------------------------
// K2: heterogeneous grid, 512 blocks = exactly 2 per CU.
// Blocks [0,256): gemm. Each block owns TWO complementary 64x64 tiles
//   (tm, p) and (tm, 31-p) -> exactly 33 BK=64 K-steps per block, balance
//   guaranteed regardless of block->CU placement. One continuous 4-stage
//   LDS pipeline (4x16KB), counted vmcnt(12) (4 loads/thread/stage, 3
//   stages in flight), raw s_barrier. No stores inside the K-loop (both
//   accumulators held in VGPRs; C written in the epilogue) so vmcnt
//   counting stays exact. 16B-chunk XOR swizzle (verified R2-R4).
// Blocks [256,512): logdet via MFMA, LDS-free.
//   ld[b,i,o] = log( sum_q eb[i,o,q] * exp(grad[b,i,q]) )
//   = log of 16x16x32 bf16 MFMA with A=exp(grad) frag, B=eb frag, C=0.
//   Operands loaded straight into fragment layout from global (L2/L3-warm).
// ---------------------------------------------------------------------------
__global__ __launch_bounds__(256) void gemm_logdet_kernel(
    const unsigned short* __restrict__ A, const unsigned short* __restrict__ W,
    const float* __restrict__ bias, const float* __restrict__ grad,
    const float* __restrict__ exp_blocks, float* __restrict__ out,
    float* __restrict__ ld)
{
  __shared__ __align__(16) char smem[4 * 16384];  // 64 KiB -> 2 blocks/CU

  int id = blockIdx.x;
  int tid = threadIdx.x;
  int lane = tid & 63, wid = tid >> 6;
  int l15 = lane & 15, lg = lane >> 4;

  if (id < 256) {
    // ================= gemm =================
    int tm = id >> 4;
    int p  = id & 15;
    int m0 = tm * 64;
    int n0a = p * 64;            // tile a: nk1 = p+1 steps
    int n0b = (31 - p) * 64;     // tile b: nk2 = 32-p steps
    int nk1 = p + 1;             // nk1 + nk2 = 33

    int wm = wid >> 1, wn = wid & 1;
    int srow = lane >> 3;            // 8 rows per staging instr
    int schunk = (lane & 7) ^ (srow & 7);

    auto stage = [&](int s) {
      int n0, kt;
      if (s < nk1) { n0 = n0a; kt = s; } else { n0 = n0b; kt = s - nk1; }
      size_t kb = (size_t)kt * 128;    // byte offset in K (BK=64 bf16)
      char* base = smem + (s & 3) * 16384;
#pragma unroll
      for (int e = 0; e < 2; ++e) {
        int sg = wid * 2 + e;          // 8 groups of 8 rows
        int row = sg * 8 + srow;
        gload_lds16((const char*)A + (size_t)(m0 + row) * 4096 + kb + schunk * 16,
                    base + sg * 1024);
        gload_lds16((const char*)W + (size_t)(n0 + row) * 4096 + kb + schunk * 16,
                    base + 8192 + sg * 1024);
      }
    };

    f32x4 acc_a[2][2] = {};
    f32x4 acc_b[2][2] = {};

    auto compute = [&](int s, f32x4 (*acc)[2]) {
      const char* sA = smem + (s & 3) * 16384;
      const char* sB = sA + 8192;
      bf16x8 af[2][2], bfr[2][2];
#pragma unroll
      for (int mi = 0; mi < 2; ++mi) {
        int row = wm * 32 + mi * 16 + l15;
#pragma unroll
        for (int ks = 0; ks < 2; ++ks) {
          int ch = (ks * 4 + lg) ^ (row & 7);
          af[mi][ks] = *(const bf16x8*)(sA + row * 128 + ch * 16);
        }
      }
#pragma unroll
      for (int ni = 0; ni < 2; ++ni) {
        int row = wn * 32 + ni * 16 + l15;
#pragma unroll
        for (int ks = 0; ks < 2; ++ks) {
          int ch = (ks * 4 + lg) ^ (row & 7);
          bfr[ni][ks] = *(const bf16x8*)(sB + row * 128 + ch * 16);
        }
      }
#pragma unroll
      for (int ks = 0; ks < 2; ++ks)
#pragma unroll
        for (int mi = 0; mi < 2; ++mi)
#pragma unroll
          for (int ni = 0; ni < 2; ++ni)
            acc[mi][ni] = __builtin_amdgcn_mfma_f32_16x16x32_bf16(
                af[mi][ks], bfr[ni][ks], acc[mi][ni], 0, 0, 0);
    };

    stage(0); stage(1); stage(2);      // 12 loads in flight
    int s = 0;
    for (; s < nk1; ++s) {             // tile a steps
      if (s + 3 < 33) stage(s + 3);
      int rem = 32 - s;
      if (rem >= 3)      asm volatile("s_waitcnt vmcnt(12)" ::: "memory");
      else if (rem == 2) asm volatile("s_waitcnt vmcnt(8)" ::: "memory");
      else if (rem == 1) asm volatile("s_waitcnt vmcnt(4)" ::: "memory");
      else               asm volatile("s_waitcnt vmcnt(0)" ::: "memory");
      __builtin_amdgcn_s_barrier();    // stage s resident
      compute(s, acc_a);
      __builtin_amdgcn_s_barrier();    // reads done before buf reuse
    }
    for (; s < 33; ++s) {              // tile b steps
      if (s + 3 < 33) stage(s + 3);
      int rem = 32 - s;
      if (rem >= 3)      asm volatile("s_waitcnt vmcnt(12)" ::: "memory");
      else if (rem == 2) asm volatile("s_waitcnt vmcnt(8)" ::: "memory");
      else if (rem == 1) asm volatile("s_waitcnt vmcnt(4)" ::: "memory");
      else               asm volatile("s_waitcnt vmcnt(0)" ::: "memory");
      __builtin_amdgcn_s_barrier();
      compute(s, acc_b);
      __builtin_amdgcn_s_barrier();
    }

    // epilogue: write both tiles (C/D: row=(lane>>4)*4+reg, col=lane&15)
#pragma unroll
    for (int t = 0; t < 2; ++t) {
      int n0 = t ? n0b : n0a;
      f32x4 (*acc)[2] = t ? acc_b : acc_a;
      float bv0 = bias[n0 + wn * 32 + l15];
      float bv1 = bias[n0 + wn * 32 + 16 + l15];
#pragma unroll
      for (int mi = 0; mi < 2; ++mi)
#pragma unroll
        for (int ni = 0; ni < 2; ++ni) {
          float bv = ni ? bv1 : bv0;
#pragma unroll
          for (int j = 0; j < 4; ++j) {
            int m = m0 + wm * 32 + mi * 16 + lg * 4 + j;
            int n = n0 + wn * 32 + ni * 16 + l15;
            out[(size_t)m * F + n] = acc[mi][ni][j] + bv;
          }
        }
    }
  } else {
    // ================= logdet (MFMA, LDS-free) =================
    int lid = id - 256;                // 0..255
    int i = lid & 63;
    int bq = lid >> 6;                 // batch quarter
    int b_base = bq * 256 + wid * 64;  // this wave: 64 batches

    // B-frags: eb[o][q], o = col = l15 (+16 for hi), q = lg*8 + j
    const float* ebp = exp_blocks + (size_t)i * 1024;
    bf16x8 eb_lo, eb_hi;
    {
      float4 a0 = *(const float4*)(ebp + l15 * 32 + lg * 8);
      float4 a1 = *(const float4*)(ebp + l15 * 32 + lg * 8 + 4);
      float4 b0 = *(const float4*)(ebp + (16 + l15) * 32 + lg * 8);
      float4 b1 = *(const float4*)(ebp + (16 + l15) * 32 + lg * 8 + 4);
      union { unsigned short s[8]; bf16x8 v; } plo, phi;
      plo.s[0] = f2bf(a0.x); plo.s[1] = f2bf(a0.y); plo.s[2] = f2bf(a0.z); plo.s[3] = f2bf(a0.w);
      plo.s[4] = f2bf(a1.x); plo.s[5] = f2bf(a1.y); plo.s[6] = f2bf(a1.z); plo.s[7] = f2bf(a1.w);
      phi.s[0] = f2bf(b0.x); phi.s[1] = f2bf(b0.y); phi.s[2] = f2bf(b0.z); phi.s[3] = f2bf(b0.w);
      phi.s[4] = f2bf(b1.x); phi.s[5] = f2bf(b1.y); phi.s[6] = f2bf(b1.z); phi.s[7] = f2bf(b1.w);
      eb_lo = plo.v; eb_hi = phi.v;
    }

    const f32x4 zero = {0.f, 0.f, 0.f, 0.f};
#pragma unroll
    for (int g = 0; g < 4; ++g) {
      // A-frag: exp(grad[b][i][q]), b-row = l15, q = lg*8 + j
      int brow = b_base + g * 16 + l15;
      const float* gp = grad + (size_t)brow * 2048 + i * 32 + lg * 8;
      float4 g0 = *(const float4*)gp;
      float4 g1 = *(const float4*)(gp + 4);
      union { unsigned short s[8]; bf16x8 v; } pg;
      pg.s[0] = f2bf(__expf(g0.x)); pg.s[1] = f2bf(__expf(g0.y));
      pg.s[2] = f2bf(__expf(g0.z)); pg.s[3] = f2bf(__expf(g0.w));
      pg.s[4] = f2bf(__expf(g1.x)); pg.s[5] = f2bf(__expf(g1.y));
      pg.s[6] = f2bf(__expf(g1.z)); pg.s[7] = f2bf(__expf(g1.w));

      f32x4 dlo = __builtin_amdgcn_mfma_f32_16x16x32_bf16(pg.v, eb_lo, zero, 0, 0, 0);
      f32x4 dhi = __builtin_amdgcn_mfma_f32_16x16x32_bf16(pg.v, eb_hi, zero, 0, 0, 0);

#pragma unroll
      for (int j = 0; j < 4; ++j) {
        int bb = b_base + g * 16 + lg * 4 + j;   // D row = (lane>>4)*4 + reg
        float* dst = ld + ((size_t)bb * 64 + i) * 32;
        dst[l15] = __logf(dlo[j]);               // D col = lane&15
        dst[16 + l15] = __logf(dhi[j]);
      }
    }
  }
}

// ---------------------------------------------------------------------------
extern "C" void kernel_launch(void* const* d_in, const int* in_sizes, int n_in,
                              void* d_out, int out_size, void* d_ws, size_t ws_size,
                              hipStream_t stream)
{
  const float* inputs = (const float*)d_in[0];
  const float* grad   = (const float*)d_in[1];
  const float* weight = (const float*)d_in[2];
  const float* dw     = (const float*)d_in[3];
  const float* bias   = (const float*)d_in[4];

  float* out = (float*)d_out;                  // 1024*2048
  float* ld  = out + (size_t)BATCH * F;        // 1024*64*32

  unsigned short* w_n  = (unsigned short*)d_ws;              // 8 MiB
  unsigned short* a_bf = w_n + (size_t)F * F;                // 4 MiB
  float* exp_blocks    = (float*)(a_bf + (size_t)BATCH * F); // 256 KiB

  prep_convert_kernel<<<1536, 256, 0, stream>>>(inputs, a_bf, weight, dw, w_n, exp_blocks);
  gemm_logdet_kernel<<<512, 256, 0, stream>>>(a_bf, w_n, bias, grad, exp_blocks, out, ld);
}

// Round 8
// 99.460 us; speedup vs baseline: 1.9554x; 1.0042x over previous
//
#include <hip/hip_runtime.h>

#define F 2048
#define BATCH 1024

typedef short bf16x8 __attribute__((ext_vector_type(8)));
typedef float f32x4 __attribute__((ext_vector_type(4)));
typedef unsigned short u16x4 __attribute__((ext_vector_type(4)));

// round-to-nearest-even f32 -> bf16 (bit trick, finite values only)
__device__ __forceinline__ unsigned short f2bf(float f) {
  unsigned u = __builtin_bit_cast(unsigned, f);
  unsigned r = (u + 0x7fffu + ((u >> 16) & 1u)) >> 16;
  return (unsigned short)r;
}

__device__ __forceinline__ void gload_lds16(const void* g, void* l) {
  __builtin_amdgcn_global_load_lds(
      (const __attribute__((address_space(1))) unsigned int*)g,
      (__attribute__((address_space(3))) unsigned int*)l,
      16, 0, 0);
}

// ---------------------------------------------------------------------------
// K1: fused prep+convert (measured 4.2 us warm / ~7 cold; logic unchanged).
// blocks [0,1024): convert inputs f32 -> bf16, 2048 elems/block.
// blocks [1024,1536): prep, one wave per weight row:
//   w = exp(weight) in diag 32-block, weight below, 0 above
//   w_n = exp(dw)*w/||w|| bf16, written for c < (r&~63)+64 (= gemm K-range)
//   exp_blocks[r,p] = exp(dw + weight[r,d0+p] - 0.5*log(wsn))
// ---------------------------------------------------------------------------
__global__ __launch_bounds__(256) void prep_convert_kernel(
    const float* __restrict__ inputs, unsigned short* __restrict__ a_bf,
    const float* __restrict__ weight, const float* __restrict__ dw,
    unsigned short* __restrict__ w_n, float* __restrict__ exp_blocks)
{
  int bid = blockIdx.x;
  if (bid < 1024) {
    int idx = bid * 2048 + threadIdx.x * 8;
    float4 v0 = *(const float4*)(inputs + idx);
    float4 v1 = *(const float4*)(inputs + idx + 4);
    union { unsigned short s[8]; bf16x8 v; } o;
    o.s[0] = f2bf(v0.x); o.s[1] = f2bf(v0.y); o.s[2] = f2bf(v0.z); o.s[3] = f2bf(v0.w);
    o.s[4] = f2bf(v1.x); o.s[5] = f2bf(v1.y); o.s[6] = f2bf(v1.z); o.s[7] = f2bf(v1.w);
    *(bf16x8*)(a_bf + idx) = o.v;
    return;
  }
  int rb = bid - 1024;
  int lane = threadIdx.x & 63;
  int r = rb * 4 + (threadIdx.x >> 6);
  int i = r >> 5;
  int lim = (i + 1) * 32;             // valid-data end (mult of 32)
  int wlim = (r & ~63) + 64;          // gemm K-range end (mult of 64)
  int d0 = i * 32;
  const float* wrow = weight + (size_t)r * F;

  float ss = 0.f;
  for (int j = lane; j < lim / 4; j += 64) {
    float4 v = ((const float4*)wrow)[j];
    if (j * 4 >= d0) {
      v.x = __expf(v.x); v.y = __expf(v.y); v.z = __expf(v.z); v.w = __expf(v.w);
    }
    ss += v.x * v.x + v.y * v.y + v.z * v.z + v.w * v.w;
  }
#pragma unroll
  for (int d = 32; d > 0; d >>= 1) ss += __shfl_xor(ss, d, 64);

  float dwr = dw[r];
  float scale = __expf(dwr) * rsqrtf(ss);
  float halflog = 0.5f * __logf(ss);

  unsigned short* onrow = w_n + (size_t)r * F;
  for (int j = lane; j < wlim / 4; j += 64) {
    u16x4 o = {0, 0, 0, 0};
    if (j * 4 < lim) {
      float4 v = ((const float4*)wrow)[j];
      if (j * 4 >= d0) {
        v.x = __expf(v.x); v.y = __expf(v.y); v.z = __expf(v.z); v.w = __expf(v.w);
      }
      o[0] = f2bf(scale * v.x); o[1] = f2bf(scale * v.y);
      o[2] = f2bf(scale * v.z); o[3] = f2bf(scale * v.w);
    }
    *(u16x4*)(onrow + j * 4) = o;
  }
  if (lane < 32) {
    exp_blocks[(size_t)r * 32 + lane] = __expf(dwr + wrow[d0 + lane] - halflog);
  }
}

// ---------------------------------------------------------------------------
// K2: 768 blocks = 3/CU (LDS 48 KB, __launch_bounds__(256,3)) so freed slots
// get backfilled -> latency hiding by TLP, no placement assumptions.
// Blocks [0,512): gemm, UNPAIRED triangular tiles, heavy-first order:
//   tn = 31-(id>>4), tm = id&15, nkt = tn+1 BK=64 steps. 32-step blocks
//   dispatch first; short blocks + logdet backfill. 3-stage LDS pipeline,
//   counted vmcnt (4 loads/thread/stage), raw s_barrier, 16B-chunk XOR
//   swizzle (verified R2-R7).
// Blocks [512,768): logdet via MFMA, LDS-free (verified R7):
//   ld[b,i,o] = log( sum_q eb[i,o,q] * exp(grad[b,i,q]) )
// ---------------------------------------------------------------------------
__global__ __launch_bounds__(256, 3) void gemm_logdet_kernel(
    const unsigned short* __restrict__ A, const unsigned short* __restrict__ W,
    const float* __restrict__ bias, const float* __restrict__ grad,
    const float* __restrict__ exp_blocks, float* __restrict__ out,
    float* __restrict__ ld)
{
  __shared__ __align__(16) char smem[3 * 16384];  // 48 KiB -> 3 blocks/CU

  int id = blockIdx.x;
  int tid = threadIdx.x;
  int lane = tid & 63, wid = tid >> 6;
  int l15 = lane & 15, lg = lane >> 4;

  if (id < 512) {
    // ================= gemm =================
    int tn = 31 - (id >> 4);         // heavy tiles dispatch first
    int tm = id & 15;
    int m0 = tm * 64, n0 = tn * 64;
    int nkt = tn + 1;

    int wm = wid >> 1, wn = wid & 1;
    int srow = lane >> 3;            // 8 rows per staging instr
    int schunk = (lane & 7) ^ (srow & 7);

    auto stage = [&](int kt) {
      size_t kb = (size_t)kt * 128;  // byte offset in K (BK=64 bf16)
      char* base = smem + (kt % 3) * 16384;
#pragma unroll
      for (int e = 0; e < 2; ++e) {
        int sg = wid * 2 + e;        // 8 groups of 8 rows
        int row = sg * 8 + srow;
        gload_lds16((const char*)A + (size_t)(m0 + row) * 4096 + kb + schunk * 16,
                    base + sg * 1024);
        gload_lds16((const char*)W + (size_t)(n0 + row) * 4096 + kb + schunk * 16,
                    base + 8192 + sg * 1024);
      }
    };

    f32x4 acc[2][2] = {};

    auto compute = [&](int kt) {
      const char* sA = smem + (kt % 3) * 16384;
      const char* sB = sA + 8192;
      bf16x8 af[2][2], bfr[2][2];
#pragma unroll
      for (int mi = 0; mi < 2; ++mi) {
        int row = wm * 32 + mi * 16 + l15;
#pragma unroll
        for (int ks = 0; ks < 2; ++ks) {
          int ch = (ks * 4 + lg) ^ (row & 7);
          af[mi][ks] = *(const bf16x8*)(sA + row * 128 + ch * 16);
        }
      }
#pragma unroll
      for (int ni = 0; ni < 2; ++ni) {
        int row = wn * 32 + ni * 16 + l15;
#pragma unroll
        for (int ks = 0; ks < 2; ++ks) {
          int ch = (ks * 4 + lg) ^ (row & 7);
          bfr[ni][ks] = *(const bf16x8*)(sB + row * 128 + ch * 16);
        }
      }
#pragma unroll
      for (int ks = 0; ks < 2; ++ks)
#pragma unroll
        for (int mi = 0; mi < 2; ++mi)
#pragma unroll
          for (int ni = 0; ni < 2; ++ni)
            acc[mi][ni] = __builtin_amdgcn_mfma_f32_16x16x32_bf16(
                af[mi][ks], bfr[ni][ks], acc[mi][ni], 0, 0, 0);
    };

    stage(0);
    if (nkt > 1) stage(1);
    for (int kt = 0; kt < nkt; ++kt) {
      if (kt + 2 < nkt) stage(kt + 2);
      int rem = nkt - 1 - kt;
      if (rem >= 2)      asm volatile("s_waitcnt vmcnt(8)" ::: "memory");
      else if (rem == 1) asm volatile("s_waitcnt vmcnt(4)" ::: "memory");
      else               asm volatile("s_waitcnt vmcnt(0)" ::: "memory");
      __builtin_amdgcn_s_barrier();  // stage kt resident in LDS
      compute(kt);
      __builtin_amdgcn_s_barrier();  // reads done before buf reuse
    }

    float bv0 = bias[n0 + wn * 32 + l15];
    float bv1 = bias[n0 + wn * 32 + 16 + l15];
#pragma unroll
    for (int mi = 0; mi < 2; ++mi)
#pragma unroll
      for (int ni = 0; ni < 2; ++ni) {
        float bv = ni ? bv1 : bv0;
#pragma unroll
        for (int j = 0; j < 4; ++j) {
          int m = m0 + wm * 32 + mi * 16 + lg * 4 + j;   // C/D: row=(lane>>4)*4+reg
          int n = n0 + wn * 32 + ni * 16 + l15;          //      col=lane&15
          out[(size_t)m * F + n] = acc[mi][ni][j] + bv;
        }
      }
  } else {
    // ================= logdet (MFMA, LDS-free) =================
    int lid = id - 512;                // 0..255
    int i = lid & 63;
    int bq = lid >> 6;                 // batch quarter
    int b_base = bq * 256 + wid * 64;  // this wave: 64 batches

    // B-frags: eb[o][q], o = col = l15 (+16 for hi), q = lg*8 + j
    const float* ebp = exp_blocks + (size_t)i * 1024;
    bf16x8 eb_lo, eb_hi;
    {
      float4 a0 = *(const float4*)(ebp + l15 * 32 + lg * 8);
      float4 a1 = *(const float4*)(ebp + l15 * 32 + lg * 8 + 4);
      float4 b0 = *(const float4*)(ebp + (16 + l15) * 32 + lg * 8);
      float4 b1 = *(const float4*)(ebp + (16 + l15) * 32 + lg * 8 + 4);
      union { unsigned short s[8]; bf16x8 v; } plo, phi;
      plo.s[0] = f2bf(a0.x); plo.s[1] = f2bf(a0.y); plo.s[2] = f2bf(a0.z); plo.s[3] = f2bf(a0.w);
      plo.s[4] = f2bf(a1.x); plo.s[5] = f2bf(a1.y); plo.s[6] = f2bf(a1.z); plo.s[7] = f2bf(a1.w);
      phi.s[0] = f2bf(b0.x); phi.s[1] = f2bf(b0.y); phi.s[2] = f2bf(b0.z); phi.s[3] = f2bf(b0.w);
      phi.s[4] = f2bf(b1.x); phi.s[5] = f2bf(b1.y); phi.s[6] = f2bf(b1.z); phi.s[7] = f2bf(b1.w);
      eb_lo = plo.v; eb_hi = phi.v;
    }

    const f32x4 zero = {0.f, 0.f, 0.f, 0.f};
#pragma unroll
    for (int g = 0; g < 4; ++g) {
      // A-frag: exp(grad[b][i][q]), b-row = l15, q = lg*8 + j
      int brow = b_base + g * 16 + l15;
      const float* gp = grad + (size_t)brow * 2048 + i * 32 + lg * 8;
      float4 g0 = *(const float4*)gp;
      float4 g1 = *(const float4*)(gp + 4);
      union { unsigned short s[8]; bf16x8 v; } pg;
      pg.s[0] = f2bf(__expf(g0.x)); pg.s[1] = f2bf(__expf(g0.y));
      pg.s[2] = f2bf(__expf(g0.z)); pg.s[3] = f2bf(__expf(g0.w));
      pg.s[4] = f2bf(__expf(g1.x)); pg.s[5] = f2bf(__expf(g1.y));
      pg.s[6] = f2bf(__expf(g1.z)); pg.s[7] = f2bf(__expf(g1.w));

      f32x4 dlo = __builtin_amdgcn_mfma_f32_16x16x32_bf16(pg.v, eb_lo, zero, 0, 0, 0);
      f32x4 dhi = __builtin_amdgcn_mfma_f32_16x16x32_bf16(pg.v, eb_hi, zero, 0, 0, 0);

#pragma unroll
      for (int j = 0; j < 4; ++j) {
        int bb = b_base + g * 16 + lg * 4 + j;   // D row = (lane>>4)*4 + reg
        float* dst = ld + ((size_t)bb * 64 + i) * 32;
        dst[l15] = __logf(dlo[j]);               // D col = lane&15
        dst[16 + l15] = __logf(dhi[j]);
      }
    }
  }
}

// ---------------------------------------------------------------------------
extern "C" void kernel_launch(void* const* d_in, const int* in_sizes, int n_in,
                              void* d_out, int out_size, void* d_ws, size_t ws_size,
                              hipStream_t stream)
{
  const float* inputs = (const float*)d_in[0];
  const float* grad   = (const float*)d_in[1];
  const float* weight = (const float*)d_in[2];
  const float* dw     = (const float*)d_in[3];
  const float* bias   = (const float*)d_in[4];

  float* out = (float*)d_out;                  // 1024*2048
  float* ld  = out + (size_t)BATCH * F;        // 1024*64*32

  unsigned short* w_n  = (unsigned short*)d_ws;              // 8 MiB
  unsigned short* a_bf = w_n + (size_t)F * F;                // 4 MiB
  float* exp_blocks    = (float*)(a_bf + (size_t)BATCH * F); // 256 KiB

  prep_convert_kernel<<<1536, 256, 0, stream>>>(inputs, a_bf, weight, dw, w_n, exp_blocks);
  gemm_logdet_kernel<<<768, 256, 0, stream>>>(a_bf, w_n, bias, grad, exp_blocks, out, ld);
}